// Round 20
// baseline (1021.407 us; speedup 1.0000x reference)
//
#include <hip/hip_runtime.h>
#include <stdint.h>

// Problem constants (from reference setup_inputs)
#define BB 4
#define SS 512
#define EE 64
#define VV 50257
#define KK 250              // k_val
#define NROWS (BB * SS)     // 2048
#define SEG 512             // per-half-row global candidate segment
#define CAP 1024            // combined per-row capacity (= 2*SEG)
#define NB 1024             // counting-sort bins
// STEP_SIZE = 0.1 -> multiply by 10; TEMP = 1.0 -> no-op

// Float-domain pre-filter threshold. P(N(0,1) >= 2.4) = 0.0082 -> E[206]/half,
// sigma ~14 (SEG=512 is ~21 sigma). Correctness does NOT depend on it: rows
// outside [KK, CAP] (incl. segment overflow) take the exact full-row fallback.
#define THRF 2.4f
#define OVFC 0x40000001u    // overflow contribution to the arrival flag

typedef float float4n __attribute__((ext_vector_type(4)));
typedef unsigned long long u64;

__device__ __forceinline__ unsigned fkey(float f) {
    // monotonic map: larger float -> larger unsigned
    unsigned u = __float_as_uint(f);
    return (u & 0x80000000u) ? ~u : (u | 0x80000000u);
}

// fast-path bin: valid for keys >= 0xC0000000 (f >= 2.0), monotone, clamped
__device__ __forceinline__ unsigned binOf(unsigned key) {
    unsigned b = (key - 0xC0000000u) >> 14;
    return b > (NB - 1u) ? (NB - 1u) : b;
}

// One block per HALF-row (4096 blocks; 2048 resident). Each streams its half,
// flushes candidates to a private global segment, and bumps a per-row arrival
// flag. The SECOND arriver runs the tail (counting-sort rank + W-gather) --
// overlapping later generations' streaming via the block scheduler.
__global__ __launch_bounds__(256, 8)
void fused_half(const float* __restrict__ gx,
                const float* __restrict__ cb,
                const float* __restrict__ W,
                const float* __restrict__ lg,
                u64* __restrict__ cand,
                unsigned* __restrict__ done,
                float* __restrict__ out0,
                float* __restrict__ out1)
{
    __shared__ u64 sorted[CAP];                // 8 KB; stream lbuf + fallback alias
    __shared__ unsigned hist[NB];              // 4 KB
    __shared__ unsigned offs[NB];              // 4 KB (fallback csum aliases)
    __shared__ unsigned top_ids[256];          // 1 KB (KK=250 used)
    __shared__ float u_s[EE];                  // u = 0.5*gx - 20*cb
    __shared__ float sCrow;                    // 0.5*gxcb - 10*cbn
    __shared__ unsigned wtot[4];
    __shared__ unsigned lcnt, sPrev, sTbin;

    const int bid = blockIdx.x, tid = threadIdx.x;
    const int row = bid >> 1, half = bid & 1;
    const float* rp = lg + (size_t)row * VV;

    if (tid < 64) {   // wave 0: row scalars + dots (hidden under stream start)
        float a = gx[(size_t)row * EE + tid];
        float b = cb[(size_t)row * EE + tid];
        u_s[tid] = 0.5f * a - 20.0f * b;
        float p1 = a * b, p2 = b * b;
        #pragma unroll
        for (int d = 32; d > 0; d >>= 1) {
            p1 += __shfl_xor(p1, d, 64);
            p2 += __shfl_xor(p2, d, 64);
        }
        if (tid == 0) sCrow = 0.5f * p1 - 10.0f * p2;
    }
    for (int j = tid; j < NB; j += 256) hist[j] = 0u;
    if (tid == 0) lcnt = 0u;
    __syncthreads();

    const unsigned p  = (4u - ((unsigned)((size_t)row * VV) & 3u)) & 3u; // 16B peel
    const unsigned F  = (VV - p) >> 2;                                   // float4s
    const unsigned F0 = F >> 1;
    const unsigned tail0 = p + 4u * F;
    const float4n* rp4 = (const float4n*)(rp + p);
    u64* lbuf = sorted;                        // stream buffer aliases sorted

    auto emit = [&](float f, unsigned col) {
        if (f >= THRF) {
            unsigned q = atomicAdd(&lcnt, 1u);
            if (q < SEG) lbuf[q] = ((u64)fkey(f) << 32) | (unsigned)(~col);
        }
    };

    // ---- stream my half: 4 loads in flight, 16-wide max guard ----
    const unsigned lo = half ? F0 : 0u;
    const unsigned hi = half ? F  : F0;
    if (half == 0 && tid < (int)p) emit(rp[tid], tid);   // peel scalars
    unsigned i = lo + tid;
    for (; i + 768u < hi; i += 1024u) {
        float4n a = __builtin_nontemporal_load(&rp4[i]);
        float4n b = __builtin_nontemporal_load(&rp4[i + 256u]);
        float4n c = __builtin_nontemporal_load(&rp4[i + 512u]);
        float4n d = __builtin_nontemporal_load(&rp4[i + 768u]);
        float t0 = fmaxf(fmaxf(a.x, a.y), a.z);
        float t1 = fmaxf(fmaxf(a.w, b.x), b.y);
        float t2 = fmaxf(fmaxf(b.z, b.w), c.x);
        float t3 = fmaxf(fmaxf(c.y, c.z), c.w);
        float t4 = fmaxf(fmaxf(d.x, d.y), d.z);
        float u0 = fmaxf(fmaxf(t0, t1), t2);
        float u1 = fmaxf(fmaxf(t3, t4), d.w);
        if (fmaxf(u0, u1) >= THRF) {
            unsigned c0 = p + 4u*i, c1 = p + 4u*(i+256u), c2 = p + 4u*(i+512u), c3 = p + 4u*(i+768u);
            emit(a.x, c0+0); emit(a.y, c0+1); emit(a.z, c0+2); emit(a.w, c0+3);
            emit(b.x, c1+0); emit(b.y, c1+1); emit(b.z, c1+2); emit(b.w, c1+3);
            emit(c.x, c2+0); emit(c.y, c2+1); emit(c.z, c2+2); emit(c.w, c2+3);
            emit(d.x, c3+0); emit(d.y, c3+1); emit(d.z, c3+2); emit(d.w, c3+3);
        }
    }
    for (; i < hi; i += 256u) {
        float4n a = __builtin_nontemporal_load(&rp4[i]);
        if (fmaxf(fmaxf(a.x, a.y), fmaxf(a.z, a.w)) >= THRF) {
            unsigned c0 = p + 4u*i;
            emit(a.x, c0+0); emit(a.y, c0+1); emit(a.z, c0+2); emit(a.w, c0+3);
        }
    }
    if (half == 1)                                        // tail scalars
        for (unsigned t = tail0 + tid; t < VV; t += 256u) emit(rp[t], t);
    __syncthreads();

    // ---- flush to private segment; release; arrival flag ----
    const unsigned nm = lcnt;
    const bool okm = (nm <= SEG);
    const unsigned m = okm ? nm : SEG;
    for (unsigned j = tid; j < m; j += 256u)
        cand[(size_t)bid * SEG + j] = lbuf[j];
    __threadfence();                 // release: my stores visible device-wide
    __syncthreads();                 // all threads' fences complete
    if (tid == 0) sPrev = atomicAdd(&done[row], okm ? nm + 1u : OVFC);
    __syncthreads();
    const unsigned prev = sPrev;
    if (prev == 0u) return;          // first arriver: peer will run the tail
    __threadfence();                 // acquire: peer's flush visible

    const bool ovf = (!okm) || (prev >= 0x40000000u);
    const unsigned no = prev - 1u;                    // peer count (if !ovf)
    const unsigned c0n = half ? no : nm;              // count of segment 2row+0
    const unsigned c1n = half ? nm : no;
    unsigned n = c0n + c1n;                           // <= CAP when !ovf

    if (!ovf && n >= KK) {
        // ========== counting-sort ranking from the two global segments ==========
        const u64* s0 = cand + (size_t)(2 * row) * SEG;
        const u64* s1 = cand + (size_t)(2 * row + 1) * SEG;
        u64 myk[4]; unsigned myb[4];
        #pragma unroll
        for (int s = 0; s < 4; ++s) {
            unsigned j = (unsigned)tid + 256u * s;
            myk[s] = 0ull; myb[s] = 0u;
            if (j < n) {
                u64 c = (j < c0n) ? s0[j] : s1[j - c0n];
                myk[s] = c;
                unsigned b = binOf((unsigned)(c >> 32)); myb[s] = b;
                atomicAdd(&hist[b], 1u);
            }
        }
        __syncthreads();

        // offs[b] = #candidates in bins > b (exclusive suffix sum)
        unsigned h0 = hist[tid*4+0], h1 = hist[tid*4+1], h2 = hist[tid*4+2], h3 = hist[tid*4+3];
        unsigned ls3 = 0, ls2 = h3, ls1 = h3 + h2, ls0 = h3 + h2 + h1;
        unsigned tot = ls0 + h0;
        const unsigned lane = (unsigned)tid & 63u, wv = (unsigned)tid >> 6;
        unsigned incl = tot;
        #pragma unroll
        for (unsigned d = 1; d < 64; d <<= 1) {
            unsigned v = __shfl_down(incl, d, 64);
            if (lane + d < 64u) incl += v;
        }
        if (lane == 0) wtot[wv] = incl;
        __syncthreads();
        unsigned above = 0;
        #pragma unroll
        for (int ww = 0; ww < 4; ++ww) if (ww > (int)wv) above += wtot[ww];
        const unsigned exclSuf = (incl - tot) + above;
        offs[tid*4+0] = exclSuf + ls0;
        offs[tid*4+1] = exclSuf + ls1;
        offs[tid*4+2] = exclSuf + ls2;
        offs[tid*4+3] = exclSuf + ls3;
        __syncthreads();

        // scatter into sorted (values live in regs; lbuf alias is dead)
        #pragma unroll
        for (int s = 0; s < 4; ++s) {
            unsigned j = (unsigned)tid + 256u * s;
            if (j < n) {
                unsigned pos = atomicAdd(&offs[myb[s]], 1u);
                sorted[pos] = myk[s];
            }
        }
        __syncthreads();

        // rank = base + #{same-bin keys > mine}; record id
        #pragma unroll
        for (int s = 0; s < 4; ++s) {
            unsigned j = (unsigned)tid + 256u * s;
            if (j < n) {
                unsigned b = myb[s], cntb = hist[b], base = offs[b] - cntb;
                u64 k = myk[s];
                unsigned r = base;
                for (unsigned t2 = base; t2 < base + cntb; ++t2)
                    r += (sorted[t2] > k) ? 1u : 0u;
                if (r < KK) top_ids[r] = ~((unsigned)k);
            }
        }
        __syncthreads();
    } else {
        // ====== EXACT FALLBACK: full-row rescan (never taken on N(0,1)) ======
        unsigned* csum = offs;
        for (int j = tid; j < NB; j += 256) hist[j] = 0u;
        if (tid == 0) lcnt = 0u;
        __syncthreads();

        if (tid < (int)p) atomicAdd(&hist[fkey(rp[tid]) >> 22], 1u);
        for (unsigned j = tid; j < F; j += 256u) {
            float4n v = rp4[j];
            atomicAdd(&hist[fkey(v.x) >> 22], 1u); atomicAdd(&hist[fkey(v.y) >> 22], 1u);
            atomicAdd(&hist[fkey(v.z) >> 22], 1u); atomicAdd(&hist[fkey(v.w) >> 22], 1u);
        }
        for (unsigned t = tail0 + tid; t < VV; t += 256u) atomicAdd(&hist[fkey(rp[t]) >> 22], 1u);
        __syncthreads();

        csum[tid] = hist[tid*4] + hist[tid*4+1] + hist[tid*4+2] + hist[tid*4+3];
        __syncthreads();
        {
            unsigned g = 0;
            for (int u2 = tid + 1; u2 < 256; ++u2) g += csum[u2];
            unsigned cs = csum[tid];
            if (g < KK && g + cs >= KK) {
                unsigned cum = g;
                #pragma unroll
                for (int b2 = 3; b2 >= 0; --b2) {
                    unsigned c2 = hist[tid*4 + b2];
                    if (cum + c2 >= KK) { sTbin = (unsigned)(tid*4 + b2); break; }
                    cum += c2;
                }
            }
        }
        __syncthreads();
        const unsigned keyT = sTbin << 22;
        __syncthreads();

        auto emit2 = [&](float f, unsigned col) {
            unsigned k = fkey(f);
            if (k >= keyT) {
                unsigned q = atomicAdd(&lcnt, 1u);
                if (q < CAP) sorted[q] = ((u64)k << 32) | (unsigned)(~col);
            }
        };
        if (tid < (int)p) emit2(rp[tid], tid);
        for (unsigned j = tid; j < F; j += 256u) {
            float4n v = rp4[j];
            unsigned ia = p + 4u*j;
            emit2(v.x, ia+0); emit2(v.y, ia+1); emit2(v.z, ia+2); emit2(v.w, ia+3);
        }
        for (unsigned t = tail0 + tid; t < VV; t += 256u) emit2(rp[t], t);
        __syncthreads();
        unsigned nf = lcnt; if (nf > CAP) nf = CAP;   // pathological mass-tie truncation
        const unsigned P4 = (nf + 3u) & ~3u;
        for (unsigned j = nf + tid; j < P4; j += 256u) sorted[j] = 0ull;
        __syncthreads();

        u64 k0 = ((unsigned)tid < nf)        ? sorted[tid]        : 0ull;
        u64 k1 = ((unsigned)tid + 256u < nf) ? sorted[tid + 256u] : 0ull;
        u64 k2 = ((unsigned)tid + 512u < nf) ? sorted[tid + 512u] : 0ull;
        u64 k3 = ((unsigned)tid + 768u < nf) ? sorted[tid + 768u] : 0ull;
        unsigned r0 = 0, r1 = 0, r2 = 0, r3 = 0;
        for (unsigned j = 0; j < P4; j += 4) {
            u64 a = sorted[j], b = sorted[j+1], c = sorted[j+2], d = sorted[j+3];
            r0 += (a > k0) + (b > k0) + (c > k0) + (d > k0);
            r1 += (a > k1) + (b > k1) + (c > k1) + (d > k1);
            r2 += (a > k2) + (b > k2) + (c > k2) + (d > k2);
            r3 += (a > k3) + (b > k3) + (c > k3) + (d > k3);
        }
        if ((unsigned)tid < nf        && r0 < KK) top_ids[r0] = ~((unsigned)k0);
        if ((unsigned)tid + 256u < nf && r1 < KK) top_ids[r1] = ~((unsigned)k1);
        if ((unsigned)tid + 512u < nf && r2 < KK) top_ids[r2] = ~((unsigned)k2);
        if ((unsigned)tid + 768u < nf && r3 < KK) top_ids[r3] = ~((unsigned)k3);
        __syncthreads();
    }

    // ---- coalesced id write + 16-lane-cooperative W gather ----
    if (tid < KK) out1[(size_t)row * KK + tid] = (float)top_ids[tid];

    const int grp = tid >> 4;
    const int l16 = tid & 15;
    const float4 u4 = *(const float4*)(u_s + 4 * l16);

    for (int k = grp; k < KK; k += 16) {
        unsigned v = top_ids[k];
        float4 w = *(const float4*)(W + (size_t)v * EE + 4 * l16);   // 256B/row coalesced
        float acc = u4.x * w.x + u4.y * w.y + u4.z * w.z + u4.w * w.w
                  + 10.0f * (w.x * w.x + w.y * w.y + w.z * w.z + w.w * w.w);
        #pragma unroll
        for (int d = 8; d >= 1; d >>= 1) acc += __shfl_xor(acc, d, 16);
        if (l16 == 0) out0[(size_t)row * KK + k] = sCrow - acc;
    }
}

extern "C" void kernel_launch(void* const* d_in, const int* in_sizes, int n_in,
                              void* d_out, int out_size, void* d_ws, size_t ws_size,
                              hipStream_t stream) {
    const float* gx = (const float*)d_in[0];      // [B,S,E]
    const float* cb = (const float*)d_in[1];      // [B,S,E]
    const float* W  = (const float*)d_in[2];      // [V,E]
    const float* lg = (const float*)d_in[3];      // [B,S,V]
    float* out0 = (float*)d_out;                       // filtered, 512000 floats
    float* out1 = out0 + (size_t)BB * SS * KK;         // ids as float, 512000

    // d_ws layout: done[2048] u32 (32 KB pad) ; cand[4096][SEG] u64 (16.8 MB)
    unsigned* done = (unsigned*)d_ws;
    u64* cand = (u64*)((char*)d_ws + 32768);

    hipMemsetAsync(done, 0, NROWS * sizeof(unsigned), stream);  // per-call flag reset
    hipLaunchKernelGGL(fused_half, dim3(2 * NROWS), dim3(256), 0, stream,
                       gx, cb, W, lg, cand, done, out0, out1);
}

// Round 21
// 88.994 us; speedup vs baseline: 11.4772x; 11.4772x over previous
//
#include <hip/hip_runtime.h>
#include <stdint.h>

// Problem constants (from reference setup_inputs)
#define BB 4
#define SS 512
#define EE 64
#define VV 50257
#define KK 250              // k_val
#define NROWS (BB * SS)     // 2048
#define CAP 1024            // per-row LDS candidate capacity (8 KB)
#define NB 1024             // counting-sort bins
// STEP_SIZE = 0.1 -> multiply by 10; TEMP = 1.0 -> no-op

// Float-domain pre-filter threshold. P(N(0,1) >= 2.4) = 0.0082 -> E[412]/row,
// sigma ~20. Correctness does NOT depend on it: rows outside [KK,CAP] take the
// in-kernel exact full-row fallback.
#define THRF 2.4f

typedef float float4n __attribute__((ext_vector_type(4)));
typedef unsigned long long u64;

__device__ __forceinline__ unsigned fkey(float f) {
    // monotonic map: larger float -> larger unsigned
    unsigned u = __float_as_uint(f);
    return (u & 0x80000000u) ? ~u : (u | 0x80000000u);
}

// fast-path bin: valid for keys >= 0xC0000000 (f >= 2.0), monotone, clamped
__device__ __forceinline__ unsigned binOf(unsigned key) {
    unsigned b = (key - 0xC0000000u) >> 14;
    return b > (NB - 1u) ? (NB - 1u) : b;
}

// Single fused kernel (round-19 structure): stream -> counting-sort rank ->
// pipelined coalesced W-gather. One block per row; 8 blocks/CU.
__global__ __launch_bounds__(256, 8)
void langevin_all(const float* __restrict__ gx,
                  const float* __restrict__ cb,
                  const float* __restrict__ W,
                  const float* __restrict__ lg,
                  float* __restrict__ out0,
                  float* __restrict__ out1)
{
    __shared__ u64 lbuf[CAP];                  // 8 KB; sorted + fallback collect alias
    __shared__ unsigned hist[NB];              // 4 KB
    __shared__ unsigned offs[NB];              // 4 KB (fallback csum aliases)
    __shared__ unsigned top_ids[256];          // 1 KB (KK=250 used)
    __shared__ float sOut[256];                // 1 KB staged out0
    __shared__ float u_s[EE];                  // u = 0.5*gx - 20*cb
    __shared__ float sCrow;                    // 0.5*gxcb - 10*cbn
    __shared__ unsigned wtot[4];
    __shared__ unsigned lcnt, sTbin;

    const int row = blockIdx.x;
    const int tid = threadIdx.x;
    const float* rp = lg + (size_t)row * VV;

    if (tid < 64) {   // wave 0: row scalars + dots (hidden under stream start)
        float a = gx[(size_t)row * EE + tid];
        float b = cb[(size_t)row * EE + tid];
        u_s[tid] = 0.5f * a - 20.0f * b;
        float p1 = a * b, p2 = b * b;
        #pragma unroll
        for (int d = 32; d > 0; d >>= 1) {
            p1 += __shfl_xor(p1, d, 64);
            p2 += __shfl_xor(p2, d, 64);
        }
        if (tid == 0) sCrow = 0.5f * p1 - 10.0f * p2;
    }
    for (int j = tid; j < NB; j += 256) hist[j] = 0u;
    if (tid == 0) lcnt = 0u;
    __syncthreads();

    const unsigned p  = (4u - ((unsigned)((size_t)row * VV) & 3u)) & 3u; // 16B-align peel
    const unsigned F  = (VV - p) >> 2;                                   // aligned float4s
    const unsigned tail0 = p + 4u * F;
    const float4n* rp4 = (const float4n*)(rp + p);

    auto emit = [&](float f, unsigned col) {
        if (f >= THRF) {
            unsigned q = atomicAdd(&lcnt, 1u);
            if (q < CAP) lbuf[q] = ((u64)fkey(f) << 32) | (unsigned)(~col);
        }
    };

    // ---- streaming filter: 4 loads in flight, 16-wide max guard ----
    if (tid < (int)p) emit(rp[tid], tid);
    unsigned i = tid;
    for (; i + 768u < F; i += 1024u) {
        float4n a = __builtin_nontemporal_load(&rp4[i]);
        float4n b = __builtin_nontemporal_load(&rp4[i + 256u]);
        float4n c = __builtin_nontemporal_load(&rp4[i + 512u]);
        float4n d = __builtin_nontemporal_load(&rp4[i + 768u]);
        float t0 = fmaxf(fmaxf(a.x, a.y), a.z);
        float t1 = fmaxf(fmaxf(a.w, b.x), b.y);
        float t2 = fmaxf(fmaxf(b.z, b.w), c.x);
        float t3 = fmaxf(fmaxf(c.y, c.z), c.w);
        float t4 = fmaxf(fmaxf(d.x, d.y), d.z);
        float u0 = fmaxf(fmaxf(t0, t1), t2);
        float u1 = fmaxf(fmaxf(t3, t4), d.w);
        if (fmaxf(u0, u1) >= THRF) {
            unsigned c0 = p + 4u*i, c1 = p + 4u*(i+256u), c2 = p + 4u*(i+512u), c3 = p + 4u*(i+768u);
            emit(a.x, c0+0); emit(a.y, c0+1); emit(a.z, c0+2); emit(a.w, c0+3);
            emit(b.x, c1+0); emit(b.y, c1+1); emit(b.z, c1+2); emit(b.w, c1+3);
            emit(c.x, c2+0); emit(c.y, c2+1); emit(c.z, c2+2); emit(c.w, c2+3);
            emit(d.x, c3+0); emit(d.y, c3+1); emit(d.z, c3+2); emit(d.w, c3+3);
        }
    }
    for (; i < F; i += 256u) {
        float4n a = __builtin_nontemporal_load(&rp4[i]);
        if (fmaxf(fmaxf(a.x, a.y), fmaxf(a.z, a.w)) >= THRF) {
            unsigned c0 = p + 4u*i;
            emit(a.x, c0+0); emit(a.y, c0+1); emit(a.z, c0+2); emit(a.w, c0+3);
        }
    }
    for (unsigned t = tail0 + tid; t < VV; t += 256u) emit(rp[t], t);
    __syncthreads();

    unsigned n = lcnt;

    if (n >= KK && n <= CAP) {
        // ========== counting-sort ranking, O(n) LDS traffic ==========
        u64 myk[4]; unsigned myb[4];
        #pragma unroll
        for (int s = 0; s < 4; ++s) {
            unsigned j = (unsigned)tid + 256u * s;
            myk[s] = 0ull; myb[s] = 0u;
            if (j < n) {
                u64 c = lbuf[j]; myk[s] = c;
                unsigned b = binOf((unsigned)(c >> 32)); myb[s] = b;
                atomicAdd(&hist[b], 1u);
            }
        }
        __syncthreads();

        // offs[b] = #candidates in bins > b (exclusive suffix sum)
        unsigned h0 = hist[tid*4+0], h1 = hist[tid*4+1], h2 = hist[tid*4+2], h3 = hist[tid*4+3];
        unsigned ls3 = 0, ls2 = h3, ls1 = h3 + h2, ls0 = h3 + h2 + h1;
        unsigned tot = ls0 + h0;
        const unsigned lane = (unsigned)tid & 63u, wv = (unsigned)tid >> 6;
        unsigned incl = tot;
        #pragma unroll
        for (unsigned d = 1; d < 64; d <<= 1) {
            unsigned v = __shfl_down(incl, d, 64);
            if (lane + d < 64u) incl += v;
        }
        if (lane == 0) wtot[wv] = incl;           // incl = sum over lanes >= lane
        __syncthreads();
        unsigned above = 0;
        #pragma unroll
        for (int ww = 0; ww < 4; ++ww) if (ww > (int)wv) above += wtot[ww];
        const unsigned exclSuf = (incl - tot) + above;
        offs[tid*4+0] = exclSuf + ls0;
        offs[tid*4+1] = exclSuf + ls1;
        offs[tid*4+2] = exclSuf + ls2;
        offs[tid*4+3] = exclSuf + ls3;
        __syncthreads();

        // scatter into sorted (aliases lbuf; values live in regs)
        u64* sorted = lbuf;
        #pragma unroll
        for (int s = 0; s < 4; ++s) {
            unsigned j = (unsigned)tid + 256u * s;
            if (j < n) {
                unsigned pos = atomicAdd(&offs[myb[s]], 1u);
                sorted[pos] = myk[s];
            }
        }
        __syncthreads();

        // rank = base + #{same-bin keys > mine}; record id at rank
        #pragma unroll
        for (int s = 0; s < 4; ++s) {
            unsigned j = (unsigned)tid + 256u * s;
            if (j < n) {
                unsigned b = myb[s], cntb = hist[b], base = offs[b] - cntb;
                u64 k = myk[s];
                unsigned r = base;
                for (unsigned t2 = base; t2 < base + cntb; ++t2)
                    r += (sorted[t2] > k) ? 1u : 0u;
                if (r < KK) top_ids[r] = ~((unsigned)k);
            }
        }
        __syncthreads();
    } else {
        // ====== EXACT FALLBACK: full-row rescan (never taken on N(0,1)) ======
        unsigned* csum = offs;
        for (int j = tid; j < NB; j += 256) hist[j] = 0u;
        if (tid == 0) lcnt = 0u;
        __syncthreads();

        if (tid < (int)p) atomicAdd(&hist[fkey(rp[tid]) >> 22], 1u);
        for (unsigned j = tid; j < F; j += 256u) {
            float4n v = rp4[j];
            atomicAdd(&hist[fkey(v.x) >> 22], 1u); atomicAdd(&hist[fkey(v.y) >> 22], 1u);
            atomicAdd(&hist[fkey(v.z) >> 22], 1u); atomicAdd(&hist[fkey(v.w) >> 22], 1u);
        }
        for (unsigned t = tail0 + tid; t < VV; t += 256u) atomicAdd(&hist[fkey(rp[t]) >> 22], 1u);
        __syncthreads();

        csum[tid] = hist[tid*4] + hist[tid*4+1] + hist[tid*4+2] + hist[tid*4+3];
        __syncthreads();
        {
            unsigned g = 0;
            for (int u2 = tid + 1; u2 < 256; ++u2) g += csum[u2];
            unsigned cs = csum[tid];
            if (g < KK && g + cs >= KK) {
                unsigned cum = g;
                #pragma unroll
                for (int b2 = 3; b2 >= 0; --b2) {
                    unsigned c2 = hist[tid*4 + b2];
                    if (cum + c2 >= KK) { sTbin = (unsigned)(tid*4 + b2); break; }
                    cum += c2;
                }
            }
        }
        __syncthreads();
        const unsigned keyT = sTbin << 22;
        __syncthreads();

        auto emit2 = [&](float f, unsigned col) {
            unsigned k = fkey(f);
            if (k >= keyT) {
                unsigned q = atomicAdd(&lcnt, 1u);
                if (q < CAP) lbuf[q] = ((u64)k << 32) | (unsigned)(~col);
            }
        };
        if (tid < (int)p) emit2(rp[tid], tid);
        for (unsigned j = tid; j < F; j += 256u) {
            float4n v = rp4[j];
            unsigned ia = p + 4u*j;
            emit2(v.x, ia+0); emit2(v.y, ia+1); emit2(v.z, ia+2); emit2(v.w, ia+3);
        }
        for (unsigned t = tail0 + tid; t < VV; t += 256u) emit2(rp[t], t);
        __syncthreads();
        unsigned nf = lcnt; if (nf > CAP) nf = CAP;   // pathological mass-tie truncation
        const unsigned P4 = (nf + 3u) & ~3u;
        for (unsigned j = nf + tid; j < P4; j += 256u) lbuf[j] = 0ull;
        __syncthreads();

        u64 k0 = ((unsigned)tid < nf)        ? lbuf[tid]        : 0ull;
        u64 k1 = ((unsigned)tid + 256u < nf) ? lbuf[tid + 256u] : 0ull;
        u64 k2 = ((unsigned)tid + 512u < nf) ? lbuf[tid + 512u] : 0ull;
        u64 k3 = ((unsigned)tid + 768u < nf) ? lbuf[tid + 768u] : 0ull;
        unsigned r0 = 0, r1 = 0, r2 = 0, r3 = 0;
        for (unsigned j = 0; j < P4; j += 4) {
            u64 a = lbuf[j], b = lbuf[j+1], c = lbuf[j+2], d = lbuf[j+3];
            r0 += (a > k0) + (b > k0) + (c > k0) + (d > k0);
            r1 += (a > k1) + (b > k1) + (c > k1) + (d > k1);
            r2 += (a > k2) + (b > k2) + (c > k2) + (d > k2);
            r3 += (a > k3) + (b > k3) + (c > k3) + (d > k3);
        }
        if ((unsigned)tid < nf        && r0 < KK) top_ids[r0] = ~((unsigned)k0);
        if ((unsigned)tid + 256u < nf && r1 < KK) top_ids[r1] = ~((unsigned)k1);
        if ((unsigned)tid + 512u < nf && r2 < KK) top_ids[r2] = ~((unsigned)k2);
        if ((unsigned)tid + 768u < nf && r3 < KK) top_ids[r3] = ~((unsigned)k3);
        __syncthreads();
    }

    // ---- coalesced id write ----
    if (tid < KK) out1[(size_t)row * KK + tid] = (float)top_ids[tid];

    // ---- epilogue: 16-lane coalesced W gather, 2 ids in flight ----
    const int grp = tid >> 4;
    const int l16 = tid & 15;
    const float4 u4 = *(const float4*)(u_s + 4 * l16);

    for (int k = grp; k < KK; k += 32) {
        const int kb = k + 16;
        const bool has1 = (kb < KK);
        unsigned v0 = top_ids[k];
        unsigned v1 = has1 ? top_ids[kb] : v0;
        float4 w0 = *(const float4*)(W + (size_t)v0 * EE + 4 * l16);   // both loads issued
        float4 w1 = *(const float4*)(W + (size_t)v1 * EE + 4 * l16);   // before reductions
        float a0 = u4.x * w0.x + u4.y * w0.y + u4.z * w0.z + u4.w * w0.w
                 + 10.0f * (w0.x * w0.x + w0.y * w0.y + w0.z * w0.z + w0.w * w0.w);
        float a1 = u4.x * w1.x + u4.y * w1.y + u4.z * w1.z + u4.w * w1.w
                 + 10.0f * (w1.x * w1.x + w1.y * w1.y + w1.z * w1.z + w1.w * w1.w);
        #pragma unroll
        for (int d = 8; d >= 1; d >>= 1) {    // independent chains interleave
            a0 += __shfl_xor(a0, d, 16);
            a1 += __shfl_xor(a1, d, 16);
        }
        if (l16 == 0) {
            sOut[k] = sCrow - a0;
            if (has1) sOut[kb] = sCrow - a1;
        }
    }
    __syncthreads();
    if (tid < KK) out0[(size_t)row * KK + tid] = sOut[tid];   // coalesced
}

extern "C" void kernel_launch(void* const* d_in, const int* in_sizes, int n_in,
                              void* d_out, int out_size, void* d_ws, size_t ws_size,
                              hipStream_t stream) {
    const float* gx = (const float*)d_in[0];      // [B,S,E]
    const float* cb = (const float*)d_in[1];      // [B,S,E]
    const float* W  = (const float*)d_in[2];      // [V,E]
    const float* lg = (const float*)d_in[3];      // [B,S,V]
    float* out0 = (float*)d_out;                       // filtered, 512000 floats
    float* out1 = out0 + (size_t)BB * SS * KK;         // ids as float, 512000

    hipLaunchKernelGGL(langevin_all, dim3(NROWS), dim3(256), 0, stream,
                       gx, cb, W, lg, out0, out1);
}